// Round 5
// baseline (215.307 us; speedup 1.0000x reference)
//
#include <hip/hip_runtime.h>
#include <hip/hip_bf16.h>

#define BZn 32
#define CAPn 134
#define SEQn 144
#define INVn 16
#define ESP 1072
#define EFT 64

// ws layout (bytes):
// 0     : g_rp   135 ints
// 540   : g_col  1072 ints
// 4828  : g_inv  134 floats
// 5376  : uB     512 bf16 (1024 B)  — H1 = AdjW@F1 fragments, K=32 pad
// 6400  : vB     512 bf16           — F1 fragments, K=32 pad
// 7424  : spB2   512 bf16           — [Wl@F0 ; Wr@F0] fragments (K=32)
// 8448  : biasf  32 floats          — bias_i[16] (bl@F0+fcb), cs[16] (colsum F1)
// 8704  : convA2 2048 bf16 (4096 B) — conv weights ⊗ F2, A-fragments
// 12800 : featB  41472 bf16 (82944) — [fWl;fWr] B-fragments (K=288)
// end 95744

typedef __attribute__((ext_vector_type(8))) short bf16x8;
typedef __attribute__((ext_vector_type(4))) short short4v;
typedef __attribute__((ext_vector_type(4))) float f32x4;

#define MFMA(a, b, c) __builtin_amdgcn_mfma_f32_16x16x32_bf16(a, b, c, 0, 0, 0)

__device__ __forceinline__ unsigned short f2bf(float f) {
    union { float f; unsigned u; } v; v.f = f;
    unsigned r = v.u + 0x7fff + ((v.u >> 16) & 1);
    return (unsigned short)(r >> 16);
}
__device__ __forceinline__ float bf2f(unsigned short h) {
    union { unsigned u; float f; } v; v.u = ((unsigned)h) << 16;
    return v.f;
}
__device__ __forceinline__ unsigned pk2(float a, float b) {
    float2 v; v.x = a; v.y = b;
    union { __hip_bfloat162 h; unsigned u; } c;
    c.h = __float22bfloat162_rn(v);
    return c.u;
}
__device__ __forceinline__ short4v pack4(f32x4 v) {
    union { unsigned u[2]; short4v s; } r;
    r.u[0] = pk2(v[0], v[1]);
    r.u[1] = pk2(v[2], v[3]);
    return r.s;
}

// grid = 10. Block 0: CSR + combos, ALL small weights LDS-staged first
// (R5 post-mortem: scattered cold scalar global loads in the combo loops were
// the ~60 µs prep cost). Blocks 1..9: featB slab kk via LDS staging.
__global__ __launch_bounds__(256) void prep_kernel(
    const int* __restrict__ ge, const int* __restrict__ fe,
    const float* __restrict__ Wl,  const float* __restrict__ Wr,
    const float* __restrict__ fWl, const float* __restrict__ fWr,
    const float* __restrict__ w1,  const float* __restrict__ w2,
    const float* __restrict__ fcw, const float* __restrict__ bl,
    const float* __restrict__ fcb,
    int* __restrict__ ws)
{
    int t = threadIdx.x;
    char* wsb = (char*)ws;
    unsigned short* uB     = (unsigned short*)(wsb + 5376);
    unsigned short* vB     = (unsigned short*)(wsb + 6400);
    unsigned short* spB2   = (unsigned short*)(wsb + 7424);
    float*          biasf  = (float*)(wsb + 8448);
    unsigned short* convA2 = (unsigned short*)(wsb + 8704);
    unsigned short* featB  = (unsigned short*)(wsb + 12800);

    if (blockIdx.x == 0) {
        int* g_rp  = ws;
        int* g_col = ws + 135;
        float* g_inv = (float*)(ws + 1207);
        // LDS-staged weights: fcw@0(768) w1@768(768) w2@1536(1280)
        // Wl@2816(256) Wr@3072(256) bl@3328(16) fcb@3344(16)
        __shared__ float swt[3360];
        __shared__ int cnt[CAPn], off[CAPn], fm[256];
        __shared__ float finv[16];

        for (int u = t; u < 768;  u += 256) swt[u]        = fcw[u];
        for (int u = t; u < 768;  u += 256) swt[768 + u]  = w1[u];
        for (int u = t; u < 1280; u += 256) swt[1536 + u] = w2[u];
        if (t < 256) swt[2816 + t] = Wl[t];
        if (t < 256) swt[3072 + t] = Wr[t];
        if (t < 16) swt[3328 + t] = bl[t];
        if (t < 16) swt[3344 + t] = fcb[t];

        for (int c0 = t; c0 < CAPn; c0 += 256) cnt[c0] = 0;
        fm[t] = 0;
        __syncthreads();
        for (int e = t; e < ESP; e += 256) atomicAdd(&cnt[ge[ESP + e]], 1);
        if (t < EFT) atomicAdd(&fm[fe[t] * 16 + fe[EFT + t]], 1);
        __syncthreads();
        if (t == 0) {
            int run = 0;
            for (int c0 = 0; c0 < CAPn; c0++) {
                off[c0] = run; g_rp[c0] = run;
                g_inv[c0] = 1.0f / fmaxf((float)cnt[c0], 1.0f);
                run += cnt[c0];
            }
            g_rp[CAPn] = run;
        }
        if (t < 16) {
            int dg = 0;
            for (int j = 0; j < 16; j++) dg += fm[j * 16 + t];
            finv[t] = 1.0f / fmaxf((float)dg, 1.0f);
        }
        __syncthreads();
        for (int c0 = t; c0 < CAPn; c0 += 256) cnt[c0] = 0;
        __syncthreads();
        for (int e = t; e < ESP; e += 256) {
            int d = ge[ESP + e];
            int p = off[d] + atomicAdd(&cnt[d], 1);
            g_col[p] = ge[e];
        }
        // combos — all operands now in LDS
        for (int u = t; u < 512; u += 256) {
            int l = u >> 3, j = u & 7, k = (l >> 4) * 8 + j, ip = l & 15;
            float vu = 0.f, vv = 0.f, vs = 0.f;
            if (k < 16) {
                for (int i = 0; i < 16; i++)
                    vu += (float)fm[k * 16 + i] * finv[i] * swt[(16 + i) * 16 + ip];
                vv = swt[(16 + k) * 16 + ip];
                for (int i = 0; i < 16; i++) vs += swt[2816 + k * 16 + i] * swt[i * 16 + ip];
            } else {
                for (int i = 0; i < 16; i++) vs += swt[3072 + (k - 16) * 16 + i] * swt[i * 16 + ip];
            }
            uB[u] = f2bf(vu); vB[u] = f2bf(vv); spB2[u] = f2bf(vs);
        }
        for (int u = t; u < 2048; u += 256) {
            int kk2 = u >> 9, l = (u >> 3) & 63, j = u & 7, q = l >> 4, o = l & 15;
            int kkp = kk2 * 2 + (q >> 1), i = (q & 1) * 8 + j;
            float v = 0.f;
            for (int o0 = 0; o0 < 16; o0++) {
                float w = (kkp < 3) ? swt[768 + (o0 * 16 + i) * 3 + kkp]
                                    : swt[1536 + (o0 * 16 + i) * 5 + (kkp - 3)];
                v += w * swt[(32 + o0) * 16 + o];
            }
            convA2[u] = f2bf(v);
        }
        if (t < 16) {
            float b0 = swt[3344 + t], c0 = 0.f;
            for (int i = 0; i < 16; i++) {
                b0 += swt[3328 + i] * swt[i * 16 + t];
                c0 += swt[(16 + i) * 16 + t];
            }
            biasf[t] = b0; biasf[16 + t] = c0;
        }
    } else {
        // featB slab kk: coalesced read -> LDS -> coalesced packed write
        __shared__ float wtile[32][145];
        int kk = blockIdx.x - 1;
        for (int u = t; u < 32 * 144; u += 256) {
            int r = u / 144, s = u - r * 144;
            int k = kk * 32 + r;
            wtile[r][s] = (k < 144) ? fWl[k * 144 + s] : fWr[(k - 144) * 144 + s];
        }
        __syncthreads();
        for (int u = t; u < 4608; u += 256) {
            int n0 = u >> 9, rem = u & 511;
            int l = rem >> 3, j = rem & 7;
            featB[(kk * 9 + n0) * 512 + rem] =
                f2bf(wtile[(l >> 4) * 8 + j][n0 * 16 + (l & 15)]);
        }
    }
}

// R9: scratch elimination. R7/R8 post-mortem: the +48B/thread WRITE excess was
// the wave-indexed const arrays (ust/ucn/...) materialized in scratch (rule:
// runtime-indexed local arrays -> private memory). Replaced with affine
// arithmetic in `wave` (wave-uniform SALU selects, scratch-impossible).
// Keep LDS alias (25088 B -> 6 blocks/CU) + spill-free launch_bounds(256,5).
__global__ __launch_bounds__(256, 5) void fused_kernel(
    const float* __restrict__ src,
    const float* __restrict__ fbl,
    const int* __restrict__ ws,
    float* __restrict__ out)
{
    const int* g_rp  = ws;
    const int* g_col = ws + 135;
    const float* g_inv = (const float*)(ws + 1207);
    const char* wsb = (const char*)ws;
    const unsigned short* uB     = (const unsigned short*)(wsb + 5376);
    const unsigned short* vB     = (const unsigned short*)(wsb + 6400);
    const unsigned short* spB2   = (const unsigned short*)(wsb + 7424);
    const float*          biasf  = (const float*)(wsb + 8448);
    const unsigned short* convA2 = (const unsigned short*)(wsb + 8704);
    const unsigned short* featB  = (const unsigned short*)(wsb + 12800);

    // ~24.5 KB LDS -> 6 blocks/CU. Strides 24/312 shorts: <=2-way banks (free).
    __shared__ __align__(16) unsigned short xs_bf[SEQn + 4][24];   // x[s][i] + conv halo
    __shared__ __align__(16) unsigned short mt_bf[SEQn][24];       // Stage A: spatial mean; Stage B/epi: conv+feat sum
    __shared__ __align__(16) unsigned short uv_bf[INVn][312];      // [U|V][i'][k=0..288)
    __shared__ float sfbl[SEQn], sbias[16], scs[16];

    int t = threadIdx.x;
    int wave = t >> 6, lane = t & 63;
    int q = lane >> 4, ln = lane & 15;

    // wave-uniform tile schedules (NO arrays -> no scratch):
    // 9 s-tiles split 3/2/2/2 over waves: starts 0,3,5,7
    int ust_w = (wave == 0) ? 0 : (2 * wave + 1);
    int ucn_w = (wave == 0) ? 3 : 2;
    // 9 s-tiles split 2/2/2/3: starts 0,2,4,6
    int sst_w = 2 * wave;
    int scn_w = (wave == 3) ? 3 : 2;

    // batch-major per XCD: concurrent blocks on an XCD share one 1.2 MB batch
    // slice -> gather re-reads are L2 hits
    int xcd  = blockIdx.x & 7;
    int slot = blockIdx.x >> 3;        // 0..535
    int bl_  = slot / 134;             // 0..3
    int c    = slot - bl_ * 134;
    int b    = xcd * 4 + bl_;
    int bc   = b * CAPn + c;
    const float* srcb = src + (size_t)b * (CAPn * SEQn * INVn);
    const float* srcc = srcb + (size_t)c * (SEQn * INVn);

    // issue own-slice staging loads first (independent of gather)
    const f32x4* s4 = (const f32x4*)srcc;
    f32x4 x0 = s4[t], x1 = s4[t + 256];
    f32x4 x2 = {0.f,0.f,0.f,0.f};
    if (t < 64) x2 = s4[t + 512];

    // ---- Stage 1: float4 gather, 4-edge unrolled ----
    int rs = g_rp[c], re = g_rp[c + 1];
    float idg = g_inv[c];
    f32x4 m0a = {0.f,0.f,0.f,0.f}, m1a = {0.f,0.f,0.f,0.f}, m2a = {0.f,0.f,0.f,0.f};
    f32x4 m0b = {0.f,0.f,0.f,0.f}, m1b = {0.f,0.f,0.f,0.f}, m2b = {0.f,0.f,0.f,0.f};
    int e = rs;
    for (; e + 3 < re; e += 4) {
        int n0_ = g_col[e], n1_ = g_col[e + 1], n2_ = g_col[e + 2], n3_ = g_col[e + 3];
        const f32x4* p0 = (const f32x4*)(srcb + (size_t)n0_ * (SEQn * INVn));
        const f32x4* p1 = (const f32x4*)(srcb + (size_t)n1_ * (SEQn * INVn));
        const f32x4* p2 = (const f32x4*)(srcb + (size_t)n2_ * (SEQn * INVn));
        const f32x4* p3 = (const f32x4*)(srcb + (size_t)n3_ * (SEQn * INVn));
        f32x4 a0 = p0[t],       a1 = p1[t],       a2 = p2[t],       a3 = p3[t];
        f32x4 b0 = p0[t + 256], b1 = p1[t + 256], b2 = p2[t + 256], b3 = p3[t + 256];
        f32x4 c0 = {0.f,0.f,0.f,0.f}, c1 = c0, c2 = c0, c3 = c0;
        if (t < 64) { c0 = p0[t + 512]; c1 = p1[t + 512]; c2 = p2[t + 512]; c3 = p3[t + 512]; }
        m0a += a0; m0b += a1; m1a += b0; m1b += b1;
        m0a += a2; m0b += a3; m1a += b2; m1b += b3;
        if (t < 64) { m2a += c0; m2b += c1; m2a += c2; m2b += c3; }
    }
    for (; e + 1 < re; e += 2) {
        int na = g_col[e], nb = g_col[e + 1];
        const f32x4* pa = (const f32x4*)(srcb + (size_t)na * (SEQn * INVn));
        const f32x4* pb = (const f32x4*)(srcb + (size_t)nb * (SEQn * INVn));
        m0a += pa[t];       m0b += pb[t];
        m1a += pa[t + 256]; m1b += pb[t + 256];
        if (t < 64) { m2a += pa[t + 512]; m2b += pb[t + 512]; }
    }
    if (e < re) {
        int na = g_col[e];
        const f32x4* pa = (const f32x4*)(srcb + (size_t)na * (SEQn * INVn));
        m0a += pa[t]; m1a += pa[t + 256];
        if (t < 64) m2a += pa[t + 512];
    }

    // hoisted tile-invariant fragments (L2-hot) — issued AFTER the gather
    bf16x8 caf[4];
    #pragma unroll
    for (int kk = 0; kk < 4; kk++)
        caf[kk] = *(const bf16x8*)(convA2 + (kk * 64 + lane) * 8);
    bf16x8 sbf = *(const bf16x8*)(spB2 + lane * 8);
    bf16x8 ubf = *(const bf16x8*)(uB + lane * 8);
    bf16x8 vbf = *(const bf16x8*)(vB + lane * 8);

    int s0g = t >> 2, i0g = (t & 3) * 4;
    f32x4 m0 = (m0a + m0b) * idg, m1 = (m1a + m1b) * idg, m2 = (m2a + m2b) * idg;
    *(short4v*)&mt_bf[s0g][i0g]      = pack4(m0);
    *(short4v*)&mt_bf[64 + s0g][i0g] = pack4(m1);
    if (t < 64) *(short4v*)&mt_bf[128 + s0g][i0g] = pack4(m2);

    *(short4v*)&xs_bf[s0g + 2][i0g]      = pack4(x0);
    *(short4v*)&xs_bf[64 + s0g + 2][i0g] = pack4(x1);
    if (t < 64) *(short4v*)&xs_bf[128 + s0g + 2][i0g] = pack4(x2);
    if (t < 64) {                                      // conv halo zeros
        int r = t >> 4, i = t & 15;
        int row = (r < 2) ? r : 144 + r;               // 0,1,146,147
        xs_bf[row][i] = 0;
    }
    if (t < SEQn) sfbl[t] = fbl[t];
    if (t < 16) { sbias[t] = biasf[t]; scs[t] = biasf[16 + t]; }
    __syncthreads();

    // ---- Stage A: U=x@H1, V=x@F1 (K=32 pad) + spatial GEMM (held in regs) ----
    for (int tt = 0; tt < ucn_w; tt++) {
        int mt = ust_w + tt;
        int sl = mt * 16 + ln;
        bf16x8 a = {0,0,0,0,0,0,0,0};
        if (q < 2) a = *(const bf16x8*)&xs_bf[sl + 2][q * 8];
        f32x4 au = {0.f,0.f,0.f,0.f}, av = {0.f,0.f,0.f,0.f};
        au = MFMA(a, ubf, au);
        av = MFMA(a, vbf, av);
        *(short4v*)&uv_bf[ln][mt * 16 + q * 4]       = pack4(au);
        *(short4v*)&uv_bf[ln][144 + mt * 16 + q * 4] = pack4(av);
    }
    f32x4 accS[3];
    for (int tt = 0; tt < scn_w; tt++) {
        int mt = sst_w + tt;
        int sl = mt * 16 + ln;
        const unsigned short* ap = (q < 2) ? &mt_bf[sl][(q & 1) * 8]
                                           : &xs_bf[sl + 2][(q & 1) * 8];
        bf16x8 a = *(const bf16x8*)ap;
        f32x4 z = {0.f,0.f,0.f,0.f};
        accS[tt] = MFMA(a, sbf, z);
    }
    __syncthreads();   // after this barrier mt_bf is dead as msp -> reused as t

    // ---- Stage B: conv (4 MFMA) + feature K=288 (9 MFMA) per s-tile ----
    for (int tt = 0; tt < ucn_w; tt++) {
        int n0 = ust_w + tt;
        int sl = n0 * 16 + ln;
        bf16x8 bfrag[9];
        #pragma unroll
        for (int kk = 0; kk < 9; kk++)
            bfrag[kk] = *(const bf16x8*)(featB + ((kk * 9 + n0) * 64 + lane) * 8);
        bf16x8 cb[4];
        #pragma unroll
        for (int kk = 0; kk < 4; kk++) {
            int kkp = kk * 2 + (q >> 1);
            int off = (kkp < 3) ? (kkp - 1) : (kkp - 5);
            cb[kk] = *(const bf16x8*)&xs_bf[sl + 2 + off][(q & 1) * 8];
        }
        f32x4 acc = {0.f,0.f,0.f,0.f};
        #pragma unroll
        for (int kk = 0; kk < 4; kk++)
            acc = MFMA(caf[kk], cb[kk], acc);
        #pragma unroll
        for (int kk = 0; kk < 9; kk++) {
            bf16x8 a = *(const bf16x8*)&uv_bf[ln][kk * 32 + q * 8];
            acc = MFMA(a, bfrag[kk], acc);
        }
        *(short4v*)&mt_bf[sl][q * 4] = pack4(acc);    // [s][i'] via C-layout scatter
    }
    __syncthreads();

    // ---- Epilogue: spatial regs + mt_bf + residual + bias, store ----
    float* outb = out + (size_t)bc * (SEQn * INVn);
    for (int tt = 0; tt < scn_w; tt++) {
        int mt = sst_w + tt;
        #pragma unroll
        for (int r = 0; r < 4; r++) {
            int s = mt * 16 + q * 4 + r;
            int idx = s * 16 + ln;
            outb[idx] = accS[tt][r] + bf2f(mt_bf[s][ln]) + srcc[idx]
                      + sbias[ln] + sfbl[s] * scs[ln];
        }
    }
}

extern "C" void kernel_launch(void* const* d_in, const int* in_sizes, int n_in,
                              void* d_out, int out_size, void* d_ws, size_t ws_size,
                              hipStream_t stream)
{
    const float* src = (const float*)d_in[0];
    const int* ge = (const int*)d_in[1];
    const int* fe = (const int*)d_in[2];
    const float* Wl  = (const float*)d_in[3];
    const float* blp = (const float*)d_in[4];
    const float* Wr  = (const float*)d_in[5];
    const float* fWl = (const float*)d_in[6];
    const float* fbl = (const float*)d_in[7];
    const float* fWr = (const float*)d_in[8];
    const float* w1  = (const float*)d_in[9];
    const float* w2  = (const float*)d_in[10];
    const float* fcw = (const float*)d_in[11];
    const float* fcb = (const float*)d_in[12];
    float* out = (float*)d_out;
    int* ws = (int*)d_ws;

    hipLaunchKernelGGL(prep_kernel, dim3(10), dim3(256), 0, stream,
                       ge, fe, Wl, Wr, fWl, fWr, w1, w2, fcw, blp, fcb, ws);
    hipLaunchKernelGGL(fused_kernel, dim3(BZn * CAPn), dim3(256), 0, stream,
                       src, fbl, ws, out);
}

// Round 6
// 160.961 us; speedup vs baseline: 1.3376x; 1.3376x over previous
//
#include <hip/hip_runtime.h>
#include <hip/hip_bf16.h>

#define BZn 32
#define CAPn 134
#define SEQn 144
#define INVn 16
#define ESP 1072
#define EFT 64

// ws layout (bytes):
// 0     : g_rp   135 ints
// 540   : g_col  1072 ints
// 4828  : g_inv  134 floats
// 5376  : uB     512 bf16 (1024 B)  — H1 = AdjW@F1 fragments, K=32 pad
// 6400  : vB     512 bf16           — F1 fragments, K=32 pad
// 7424  : spB2   512 bf16           — [Wl@F0 ; Wr@F0] fragments (K=32)
// 8448  : biasf  32 floats          — bias_i[16] (bl@F0+fcb), cs[16] (colsum F1)
// 8704  : convA2 2048 bf16 (4096 B) — conv weights ⊗ F2, A-fragments
// 12800 : featB  41472 bf16 (82944) — [fWl;fWr] B-fragments (K=288)
// end 95744

typedef __attribute__((ext_vector_type(8))) short bf16x8;
typedef __attribute__((ext_vector_type(4))) short short4v;
typedef __attribute__((ext_vector_type(4))) float f32x4;

#define MFMA(a, b, c) __builtin_amdgcn_mfma_f32_16x16x32_bf16(a, b, c, 0, 0, 0)

__device__ __forceinline__ unsigned short f2bf(float f) {
    union { float f; unsigned u; } v; v.f = f;
    unsigned r = v.u + 0x7fff + ((v.u >> 16) & 1);
    return (unsigned short)(r >> 16);
}
__device__ __forceinline__ float bf2f(unsigned short h) {
    union { unsigned u; float f; } v; v.u = ((unsigned)h) << 16;
    return v.f;
}
__device__ __forceinline__ unsigned pk2(float a, float b) {
    float2 v; v.x = a; v.y = b;
    union { __hip_bfloat162 h; unsigned u; } c;
    c.h = __float22bfloat162_rn(v);
    return c.u;
}
__device__ __forceinline__ short4v pack4(f32x4 v) {
    union { unsigned u[2]; short4v s; } r;
    r.u[0] = pk2(v[0], v[1]);
    r.u[1] = pk2(v[2], v[3]);
    return r.s;
}

// grid = 10. Block 0: CSR + combos, ALL small weights LDS-staged first
// (R5 post-mortem: scattered cold scalar global loads in the combo loops were
// the ~60 µs prep cost). Blocks 1..9: featB slab kk via LDS staging.
__global__ __launch_bounds__(256) void prep_kernel(
    const int* __restrict__ ge, const int* __restrict__ fe,
    const float* __restrict__ Wl,  const float* __restrict__ Wr,
    const float* __restrict__ fWl, const float* __restrict__ fWr,
    const float* __restrict__ w1,  const float* __restrict__ w2,
    const float* __restrict__ fcw, const float* __restrict__ bl,
    const float* __restrict__ fcb,
    int* __restrict__ ws)
{
    int t = threadIdx.x;
    char* wsb = (char*)ws;
    unsigned short* uB     = (unsigned short*)(wsb + 5376);
    unsigned short* vB     = (unsigned short*)(wsb + 6400);
    unsigned short* spB2   = (unsigned short*)(wsb + 7424);
    float*          biasf  = (float*)(wsb + 8448);
    unsigned short* convA2 = (unsigned short*)(wsb + 8704);
    unsigned short* featB  = (unsigned short*)(wsb + 12800);

    if (blockIdx.x == 0) {
        int* g_rp  = ws;
        int* g_col = ws + 135;
        float* g_inv = (float*)(ws + 1207);
        // LDS-staged weights: fcw@0(768) w1@768(768) w2@1536(1280)
        // Wl@2816(256) Wr@3072(256) bl@3328(16) fcb@3344(16)
        __shared__ float swt[3360];
        __shared__ int cnt[CAPn], off[CAPn], fm[256];
        __shared__ float finv[16];

        for (int u = t; u < 768;  u += 256) swt[u]        = fcw[u];
        for (int u = t; u < 768;  u += 256) swt[768 + u]  = w1[u];
        for (int u = t; u < 1280; u += 256) swt[1536 + u] = w2[u];
        if (t < 256) swt[2816 + t] = Wl[t];
        if (t < 256) swt[3072 + t] = Wr[t];
        if (t < 16) swt[3328 + t] = bl[t];
        if (t < 16) swt[3344 + t] = fcb[t];

        for (int c0 = t; c0 < CAPn; c0 += 256) cnt[c0] = 0;
        fm[t] = 0;
        __syncthreads();
        for (int e = t; e < ESP; e += 256) atomicAdd(&cnt[ge[ESP + e]], 1);
        if (t < EFT) atomicAdd(&fm[fe[t] * 16 + fe[EFT + t]], 1);
        __syncthreads();
        if (t == 0) {
            int run = 0;
            for (int c0 = 0; c0 < CAPn; c0++) {
                off[c0] = run; g_rp[c0] = run;
                g_inv[c0] = 1.0f / fmaxf((float)cnt[c0], 1.0f);
                run += cnt[c0];
            }
            g_rp[CAPn] = run;
        }
        if (t < 16) {
            int dg = 0;
            for (int j = 0; j < 16; j++) dg += fm[j * 16 + t];
            finv[t] = 1.0f / fmaxf((float)dg, 1.0f);
        }
        __syncthreads();
        for (int c0 = t; c0 < CAPn; c0 += 256) cnt[c0] = 0;
        __syncthreads();
        for (int e = t; e < ESP; e += 256) {
            int d = ge[ESP + e];
            int p = off[d] + atomicAdd(&cnt[d], 1);
            g_col[p] = ge[e];
        }
        // combos — all operands now in LDS
        for (int u = t; u < 512; u += 256) {
            int l = u >> 3, j = u & 7, k = (l >> 4) * 8 + j, ip = l & 15;
            float vu = 0.f, vv = 0.f, vs = 0.f;
            if (k < 16) {
                for (int i = 0; i < 16; i++)
                    vu += (float)fm[k * 16 + i] * finv[i] * swt[(16 + i) * 16 + ip];
                vv = swt[(16 + k) * 16 + ip];
                for (int i = 0; i < 16; i++) vs += swt[2816 + k * 16 + i] * swt[i * 16 + ip];
            } else {
                for (int i = 0; i < 16; i++) vs += swt[3072 + (k - 16) * 16 + i] * swt[i * 16 + ip];
            }
            uB[u] = f2bf(vu); vB[u] = f2bf(vv); spB2[u] = f2bf(vs);
        }
        for (int u = t; u < 2048; u += 256) {
            int kk2 = u >> 9, l = (u >> 3) & 63, j = u & 7, q = l >> 4, o = l & 15;
            int kkp = kk2 * 2 + (q >> 1), i = (q & 1) * 8 + j;
            float v = 0.f;
            for (int o0 = 0; o0 < 16; o0++) {
                float w = (kkp < 3) ? swt[768 + (o0 * 16 + i) * 3 + kkp]
                                    : swt[1536 + (o0 * 16 + i) * 5 + (kkp - 3)];
                v += w * swt[(32 + o0) * 16 + o];
            }
            convA2[u] = f2bf(v);
        }
        if (t < 16) {
            float b0 = swt[3344 + t], c0 = 0.f;
            for (int i = 0; i < 16; i++) {
                b0 += swt[3328 + i] * swt[i * 16 + t];
                c0 += swt[(16 + i) * 16 + t];
            }
            biasf[t] = b0; biasf[16 + t] = c0;
        }
    } else {
        // featB slab kk: coalesced read -> LDS -> coalesced packed write
        __shared__ float wtile[32][145];
        int kk = blockIdx.x - 1;
        for (int u = t; u < 32 * 144; u += 256) {
            int r = u / 144, s = u - r * 144;
            int k = kk * 32 + r;
            wtile[r][s] = (k < 144) ? fWl[k * 144 + s] : fWr[(k - 144) * 144 + s];
        }
        __syncthreads();
        for (int u = t; u < 4608; u += 256) {
            int n0 = u >> 9, rem = u & 511;
            int l = rem >> 3, j = rem & 7;
            featB[(kk * 9 + n0) * 512 + rem] =
                f2bf(wtile[(l >> 4) * 8 + j][n0 * 16 + (l & 15)]);
        }
    }
}

// R10: clean-base + alias. History: (256,4)+4-wide gather was scratch-free
// (R2: FETCH 19.7/WRITE 38.6); (256,5|6) + same code spilled (FETCH/WRITE
// blew up 3-4x, occupancy-independent => scratch). So: keep (256,4) — the
// allocator picks ~56 VGPR naturally, <=64 -> 8 waves/EU possible -> the
// LDS alias (24.7 KB -> 6 blocks/CU) becomes the binding residency limit.
// Defensively, all local arrays now compile-time-indexed (rule #20):
// accS -> named scalars; wave-tile loops -> fixed trip 3 + uniform predicate.
__global__ __launch_bounds__(256, 4) void fused_kernel(
    const float* __restrict__ src,
    const float* __restrict__ fbl,
    const int* __restrict__ ws,
    float* __restrict__ out)
{
    const int* g_rp  = ws;
    const int* g_col = ws + 135;
    const float* g_inv = (const float*)(ws + 1207);
    const char* wsb = (const char*)ws;
    const unsigned short* uB     = (const unsigned short*)(wsb + 5376);
    const unsigned short* vB     = (const unsigned short*)(wsb + 6400);
    const unsigned short* spB2   = (const unsigned short*)(wsb + 7424);
    const float*          biasf  = (const float*)(wsb + 8448);
    const unsigned short* convA2 = (const unsigned short*)(wsb + 8704);
    const unsigned short* featB  = (const unsigned short*)(wsb + 12800);

    // ~24.7 KB LDS -> 6 blocks/CU. Strides 24/312 shorts: <=2-way banks (free).
    __shared__ __align__(16) unsigned short xs_bf[SEQn + 4][24];   // x[s][i] + conv halo
    __shared__ __align__(16) unsigned short mt_bf[SEQn][24];       // Stage A: spatial mean; Stage B/epi: conv+feat sum
    __shared__ __align__(16) unsigned short uv_bf[INVn][312];      // [U|V][i'][k=0..288)
    __shared__ float sfbl[SEQn], sbias[16], scs[16];

    int t = threadIdx.x;
    int wave = t >> 6, lane = t & 63;
    int q = lane >> 4, ln = lane & 15;

    // wave-uniform tile schedules (no arrays):
    // Stage A/B: 9 s-tiles split 3/2/2/2, starts 0,3,5,7
    int ust_w = (wave == 0) ? 0 : (2 * wave + 1);
    // spatial/epilogue: split 2/2/2/3, starts 0,2,4,6
    int sst_w = 2 * wave;

    // batch-major per XCD: concurrent blocks on an XCD share one 1.2 MB batch
    // slice -> gather re-reads are L2 hits
    int xcd  = blockIdx.x & 7;
    int slot = blockIdx.x >> 3;        // 0..535
    int bl_  = slot / 134;             // 0..3
    int c    = slot - bl_ * 134;
    int b    = xcd * 4 + bl_;
    int bc   = b * CAPn + c;
    const float* srcb = src + (size_t)b * (CAPn * SEQn * INVn);
    const float* srcc = srcb + (size_t)c * (SEQn * INVn);

    // issue own-slice staging loads first (independent of gather)
    const f32x4* s4 = (const f32x4*)srcc;
    f32x4 x0 = s4[t], x1 = s4[t + 256];
    f32x4 x2 = {0.f,0.f,0.f,0.f};
    if (t < 64) x2 = s4[t + 512];

    // ---- Stage 1: float4 gather, 4-edge unrolled ----
    int rs = g_rp[c], re = g_rp[c + 1];
    float idg = g_inv[c];
    f32x4 m0a = {0.f,0.f,0.f,0.f}, m1a = {0.f,0.f,0.f,0.f}, m2a = {0.f,0.f,0.f,0.f};
    f32x4 m0b = {0.f,0.f,0.f,0.f}, m1b = {0.f,0.f,0.f,0.f}, m2b = {0.f,0.f,0.f,0.f};
    int e = rs;
    for (; e + 3 < re; e += 4) {
        int n0_ = g_col[e], n1_ = g_col[e + 1], n2_ = g_col[e + 2], n3_ = g_col[e + 3];
        const f32x4* p0 = (const f32x4*)(srcb + (size_t)n0_ * (SEQn * INVn));
        const f32x4* p1 = (const f32x4*)(srcb + (size_t)n1_ * (SEQn * INVn));
        const f32x4* p2 = (const f32x4*)(srcb + (size_t)n2_ * (SEQn * INVn));
        const f32x4* p3 = (const f32x4*)(srcb + (size_t)n3_ * (SEQn * INVn));
        f32x4 a0 = p0[t],       a1 = p1[t],       a2 = p2[t],       a3 = p3[t];
        f32x4 b0 = p0[t + 256], b1 = p1[t + 256], b2 = p2[t + 256], b3 = p3[t + 256];
        f32x4 c0 = {0.f,0.f,0.f,0.f}, c1 = c0, c2 = c0, c3 = c0;
        if (t < 64) { c0 = p0[t + 512]; c1 = p1[t + 512]; c2 = p2[t + 512]; c3 = p3[t + 512]; }
        m0a += a0; m0b += a1; m1a += b0; m1b += b1;
        m0a += a2; m0b += a3; m1a += b2; m1b += b3;
        if (t < 64) { m2a += c0; m2b += c1; m2a += c2; m2b += c3; }
    }
    for (; e + 1 < re; e += 2) {
        int na = g_col[e], nb = g_col[e + 1];
        const f32x4* pa = (const f32x4*)(srcb + (size_t)na * (SEQn * INVn));
        const f32x4* pb = (const f32x4*)(srcb + (size_t)nb * (SEQn * INVn));
        m0a += pa[t];       m0b += pb[t];
        m1a += pa[t + 256]; m1b += pb[t + 256];
        if (t < 64) { m2a += pa[t + 512]; m2b += pb[t + 512]; }
    }
    if (e < re) {
        int na = g_col[e];
        const f32x4* pa = (const f32x4*)(srcb + (size_t)na * (SEQn * INVn));
        m0a += pa[t]; m1a += pa[t + 256];
        if (t < 64) m2a += pa[t + 512];
    }

    // hoisted tile-invariant fragments (L2-hot) — issued AFTER the gather
    bf16x8 caf0 = *(const bf16x8*)(convA2 + (0 * 64 + lane) * 8);
    bf16x8 caf1 = *(const bf16x8*)(convA2 + (1 * 64 + lane) * 8);
    bf16x8 caf2 = *(const bf16x8*)(convA2 + (2 * 64 + lane) * 8);
    bf16x8 caf3 = *(const bf16x8*)(convA2 + (3 * 64 + lane) * 8);
    bf16x8 sbf = *(const bf16x8*)(spB2 + lane * 8);
    bf16x8 ubf = *(const bf16x8*)(uB + lane * 8);
    bf16x8 vbf = *(const bf16x8*)(vB + lane * 8);

    int s0g = t >> 2, i0g = (t & 3) * 4;
    f32x4 m0 = (m0a + m0b) * idg, m1 = (m1a + m1b) * idg, m2 = (m2a + m2b) * idg;
    *(short4v*)&mt_bf[s0g][i0g]      = pack4(m0);
    *(short4v*)&mt_bf[64 + s0g][i0g] = pack4(m1);
    if (t < 64) *(short4v*)&mt_bf[128 + s0g][i0g] = pack4(m2);

    *(short4v*)&xs_bf[s0g + 2][i0g]      = pack4(x0);
    *(short4v*)&xs_bf[64 + s0g + 2][i0g] = pack4(x1);
    if (t < 64) *(short4v*)&xs_bf[128 + s0g + 2][i0g] = pack4(x2);
    if (t < 64) {                                      // conv halo zeros
        int r = t >> 4, i = t & 15;
        int row = (r < 2) ? r : 144 + r;               // 0,1,146,147
        xs_bf[row][i] = 0;
    }
    if (t < SEQn) sfbl[t] = fbl[t];
    if (t < 16) { sbias[t] = biasf[t]; scs[t] = biasf[16 + t]; }
    __syncthreads();

    // ---- Stage A: U=x@H1, V=x@F1 (K=32 pad) — fixed trip 3, uniform guard ----
    #pragma unroll
    for (int tt = 0; tt < 3; tt++) {
        if ((wave == 0) || (tt < 2)) {
            int mt = ust_w + tt;
            int sl = mt * 16 + ln;
            bf16x8 a = {0,0,0,0,0,0,0,0};
            if (q < 2) a = *(const bf16x8*)&xs_bf[sl + 2][q * 8];
            f32x4 au = {0.f,0.f,0.f,0.f}, av = {0.f,0.f,0.f,0.f};
            au = MFMA(a, ubf, au);
            av = MFMA(a, vbf, av);
            *(short4v*)&uv_bf[ln][mt * 16 + q * 4]       = pack4(au);
            *(short4v*)&uv_bf[ln][144 + mt * 16 + q * 4] = pack4(av);
        }
    }
    // ---- spatial GEMM: named accumulators (no runtime-indexed array) ----
    f32x4 accS0 = {0.f,0.f,0.f,0.f}, accS1 = accS0, accS2 = accS0;
    {
        int sl = (sst_w + 0) * 16 + ln;
        const unsigned short* ap = (q < 2) ? &mt_bf[sl][(q & 1) * 8]
                                           : &xs_bf[sl + 2][(q & 1) * 8];
        accS0 = MFMA(*(const bf16x8*)ap, sbf, accS0);
    }
    {
        int sl = (sst_w + 1) * 16 + ln;
        const unsigned short* ap = (q < 2) ? &mt_bf[sl][(q & 1) * 8]
                                           : &xs_bf[sl + 2][(q & 1) * 8];
        accS1 = MFMA(*(const bf16x8*)ap, sbf, accS1);
    }
    if (wave == 3) {
        int sl = (sst_w + 2) * 16 + ln;
        const unsigned short* ap = (q < 2) ? &mt_bf[sl][(q & 1) * 8]
                                           : &xs_bf[sl + 2][(q & 1) * 8];
        accS2 = MFMA(*(const bf16x8*)ap, sbf, accS2);
    }
    __syncthreads();   // after this barrier mt_bf is dead as msp -> reused as t

    // ---- Stage B: conv (4 MFMA) + feature K=288 (9 MFMA) per s-tile ----
    #pragma unroll
    for (int tt = 0; tt < 3; tt++) {
        if ((wave == 0) || (tt < 2)) {
            int n0 = ust_w + tt;
            int sl = n0 * 16 + ln;
            bf16x8 bfrag[9];
            #pragma unroll
            for (int kk = 0; kk < 9; kk++)
                bfrag[kk] = *(const bf16x8*)(featB + ((kk * 9 + n0) * 64 + lane) * 8);
            bf16x8 cb[4];
            #pragma unroll
            for (int kk = 0; kk < 4; kk++) {
                int kkp = kk * 2 + (q >> 1);
                int off = (kkp < 3) ? (kkp - 1) : (kkp - 5);
                cb[kk] = *(const bf16x8*)&xs_bf[sl + 2 + off][(q & 1) * 8];
            }
            f32x4 acc = {0.f,0.f,0.f,0.f};
            acc = MFMA(caf0, cb[0], acc);
            acc = MFMA(caf1, cb[1], acc);
            acc = MFMA(caf2, cb[2], acc);
            acc = MFMA(caf3, cb[3], acc);
            #pragma unroll
            for (int kk = 0; kk < 9; kk++) {
                bf16x8 a = *(const bf16x8*)&uv_bf[ln][kk * 32 + q * 8];
                acc = MFMA(a, bfrag[kk], acc);
            }
            *(short4v*)&mt_bf[sl][q * 4] = pack4(acc);  // [s][i'] via C-layout scatter
        }
    }
    __syncthreads();

    // ---- Epilogue: spatial regs + mt_bf + residual + bias, store ----
    float* outb = out + (size_t)bc * (SEQn * INVn);
    {
        int mt = sst_w + 0;
        #pragma unroll
        for (int r = 0; r < 4; r++) {
            int s = mt * 16 + q * 4 + r;
            int idx = s * 16 + ln;
            outb[idx] = accS0[r] + bf2f(mt_bf[s][ln]) + srcc[idx]
                      + sbias[ln] + sfbl[s] * scs[ln];
        }
    }
    {
        int mt = sst_w + 1;
        #pragma unroll
        for (int r = 0; r < 4; r++) {
            int s = mt * 16 + q * 4 + r;
            int idx = s * 16 + ln;
            outb[idx] = accS1[r] + bf2f(mt_bf[s][ln]) + srcc[idx]
                      + sbias[ln] + sfbl[s] * scs[ln];
        }
    }
    if (wave == 3) {
        int mt = sst_w + 2;
        #pragma unroll
        for (int r = 0; r < 4; r++) {
            int s = mt * 16 + q * 4 + r;
            int idx = s * 16 + ln;
            outb[idx] = accS2[r] + bf2f(mt_bf[s][ln]) + srcc[idx]
                      + sbias[ln] + sfbl[s] * scs[ln];
        }
    }
}

extern "C" void kernel_launch(void* const* d_in, const int* in_sizes, int n_in,
                              void* d_out, int out_size, void* d_ws, size_t ws_size,
                              hipStream_t stream)
{
    const float* src = (const float*)d_in[0];
    const int* ge = (const int*)d_in[1];
    const int* fe = (const int*)d_in[2];
    const float* Wl  = (const float*)d_in[3];
    const float* blp = (const float*)d_in[4];
    const float* Wr  = (const float*)d_in[5];
    const float* fWl = (const float*)d_in[6];
    const float* fbl = (const float*)d_in[7];
    const float* fWr = (const float*)d_in[8];
    const float* w1  = (const float*)d_in[9];
    const float* w2  = (const float*)d_in[10];
    const float* fcw = (const float*)d_in[11];
    const float* fcb = (const float*)d_in[12];
    float* out = (float*)d_out;
    int* ws = (int*)d_ws;

    hipLaunchKernelGGL(prep_kernel, dim3(10), dim3(256), 0, stream,
                       ge, fe, Wl, Wr, fWl, fWr, w1, w2, fcw, blp, fcb, ws);
    hipLaunchKernelGGL(fused_kernel, dim3(BZn * CAPn), dim3(256), 0, stream,
                       src, fbl, ws, out);
}